// Round 5
// baseline (50.092 us; speedup 1.0000x reference)
//
#include <hip/hip_runtime.h>

// Problem: B=8, C=128, H=W=256, V=32.
// out[b][c][v] = max over pixels p of encoded[b][c][p] where masks[b][p] == v+1.
// encoded: (B,C,H,W) f32; masks: (B,1,H,W) int32 in [1,32]; out: (B,C,V,1) f32.
//
// Memory-bound: 268 MB encoded streamed once from HBM (~43us floor at 6.3TB/s).
// History: nt-loads HURT (-12%, r3); XCD swizzle neutral (r4) -> masks already
// L2-resident. This round: TPB 256->512 with thread-PAIR-shared LDS slot
// arrays (same 33.8KB/block) -> 4 blocks x 8 waves = 32 waves/CU (was 16),
// doubling outstanding loads.

#define NSEG 32
#define TPB  512
#define PIX  65536       // H*W
#define PIX4 (PIX/4)     // float4s per (b,c)
#define NARR (TPB/2)     // 256 slot arrays, shared by thread pairs
#define NEG_INF_KEY 0x007FFFFFu   // monotone key of -inf

// monotone map: float bits -> unsigned key preserving < ordering
__device__ __forceinline__ unsigned fkey(float f) {
    unsigned u = __float_as_uint(f);
    return u ^ (unsigned)(((int)u >> 31) | 0x80000000);
}

__global__ __launch_bounds__(TPB, 8) void VectorsFromMaskV2_kernel(
    const float4* __restrict__ enc,
    const int4*  __restrict__ masks,
    float* __restrict__ out)
{
    // 256 slot arrays (one per thread PAIR), stride 33 to spread banks:
    // bank = ((tid>>1)*33 + slot) % 32 = ((tid>>1) + slot) % 32
    __shared__ unsigned lmax[NARR * 33];  // 33792 B -> 4 blocks/CU, 32 waves/CU
    __shared__ unsigned part[16 * NSEG];  //  2048 B

    const int tid = threadIdx.x;
    const int bc  = blockIdx.x;           // b*128 + c
    const int b   = bc >> 7;

    #pragma unroll
    for (int i = tid; i < NARR * 33; i += TPB) lmax[i] = NEG_INF_KEY;
    __syncthreads();

    const float4* __restrict__ ep = enc   + (size_t)bc * PIX4;
    const int4*  __restrict__ mp = masks + (size_t)b  * PIX4;
    const int base = (tid >> 1) * 33 - 1; // id in [1..32] -> slot base+id

    #pragma unroll 4
    for (int it = 0; it < PIX4 / TPB; ++it) {
        const int i = it * TPB + tid;     // coalesced: lane i reads float4 i
        float4 e = ep[i];
        int4   m = mp[i];                 // L2-resident
        atomicMax(&lmax[base + m.x], fkey(e.x));   // ds_max_u32, no rtn
        atomicMax(&lmax[base + m.y], fkey(e.y));
        atomicMax(&lmax[base + m.z], fkey(e.z));
        atomicMax(&lmax[base + m.w], fkey(e.w));
    }
    __syncthreads();

    // stage 1: 16 groups of 32 threads; group g reduces arrays
    // [g*16, g*16+16) for segment v = tid&31. bank = (a + v) % 32 -> 2-way max.
    const int v = tid & 31, g = tid >> 5;
    unsigned k = NEG_INF_KEY;
    #pragma unroll
    for (int i = 0; i < NARR / 16; ++i) {
        unsigned t = lmax[(g * (NARR / 16) + i) * 33 + v];
        k = (t > k) ? t : k;
    }
    part[(g << 5) | v] = k;
    __syncthreads();

    // stage 2: 32 threads fold the 16 group partials, unmap key, write out
    if (tid < NSEG) {
        unsigned kk = part[tid];
        #pragma unroll
        for (int g2 = 1; g2 < 16; ++g2) {
            unsigned t = part[(g2 << 5) | tid];
            kk = (t > kk) ? t : kk;
        }
        unsigned m2 = (kk & 0x80000000u) ? 0x80000000u : 0xFFFFFFFFu;
        out[bc * NSEG + tid] = __uint_as_float(kk ^ m2);
    }
}

extern "C" void kernel_launch(void* const* d_in, const int* in_sizes, int n_in,
                              void* d_out, int out_size, void* d_ws, size_t ws_size,
                              hipStream_t stream) {
    const float4* enc   = (const float4*)d_in[0];
    const int4*   masks = (const int4*)d_in[1];
    float* out = (float*)d_out;
    // grid: one block per (b, c) pair = 8*128 = 1024 blocks
    VectorsFromMaskV2_kernel<<<1024, TPB, 0, stream>>>(enc, masks, out);
}